// Round 11
// baseline (260.586 us; speedup 1.0000x reference)
//
#include <hip/hip_runtime.h>

// EquivariantLinear: out[pos, c, m] = pw * sum_k x[pos, k, m] * W_{l(m)}[k, c]
// pos = 32768, C_IN = C_OUT = 256, FEAT = 9 (irreps 1,3,5), pw = 1/16.
// R13: zero-register DMA pipeline via global_load_lds.
//  - 256 persistent blocks x 512 thr (8 waves), 1 block/CU, NT=16 tiles of
//    POSB=8. LDS = raw fp32 tile (73728 B, linear, DMA target) + bf16 image
//    [9][8][264] (38016 B) = 111744 B.
//  - Per tile: compute(bf16) | bar | DMA(tile+1 -> raw, 9x global_load_lds
//    per thread, ZERO VGPR cost) | outstage (10 nt stores) |
//    s_waitcnt vmcnt(10)  (drains DMA, oldest-first; own stores keep flying)
//    | bar | convert raw->bf16 (LDS->LDS, no HBM) | bar.
//    HBM reads fly across compute+outstage -> read duty ~continuous.
//  - POSB=8 -> R9's within-irrep m-packing (T0{m0} T1{m1,m2} T2{m3} T3{m4,m5}
//    T4{m6,m7} T5{m8}; 1.33x MFMA on a 7.7%-busy pipe). 8 waves x 32 ch.
//  - No __syncthreads in the loop (raw s_barrier + lgkmcnt(0) only).

typedef float f32x4 __attribute__((ext_vector_type(4)));
typedef float f32x4u __attribute__((ext_vector_type(4), aligned(4)));
typedef short s16x8 __attribute__((ext_vector_type(8)));

#define POSB 8
#define XS_KS 264                     // padded k-stride (elems)
#define XS_MS (POSB * XS_KS)          // 2112 elems per m-plane
#define RAW_BYTES (POSB * 2304 * 4)   // 73728 B raw fp32 tile
#define BF16_BYTES (9 * XS_MS * 2)    // 38016 B
#define SMEM_BYTES (RAW_BYTES + BF16_BYTES)  // 111744 B -> 1 block/CU
#define STG_ROW 148                   // out-stage row stride (floats); 144 used
// per-wave out-stage chunk: 8*148*4 = 4736 B; 8 waves = 37888 <= 38016
#define NT 16                         // tiles per block; 256 x 16 = 4096 tiles
#define TILE_FLOATS (POSB * 2304)     // 18432

typedef __attribute__((address_space(3))) unsigned int lds_u32;
typedef __attribute__((address_space(1))) const unsigned int glb_u32;

__device__ __forceinline__ void dma16(const float* g, char* l_) {
  __builtin_amdgcn_global_load_lds((glb_u32*)g, (lds_u32*)l_, 16, 0, 0);
}

__device__ __forceinline__ unsigned short f2bf(float f) {
  unsigned u = __float_as_uint(f);
  return (unsigned short)((u + 0x7FFFu + ((u >> 16) & 1u)) >> 16);
}

__device__ __forceinline__ unsigned cvt_pk_bf16(float lo, float hi) {
  unsigned r;
  asm("v_cvt_pk_bf16_f32 %0, %1, %2" : "=v"(r) : "v"(lo), "v"(hi));
  return r;
}

// raw barrier: LDS ordering only, no vmcnt drain (stores/DMA stay in flight)
__device__ __forceinline__ void bar_nodrain() {
  asm volatile("s_waitcnt lgkmcnt(0)\n\ts_barrier" ::: "memory");
}

// ---- prep: W^T bf16 image in ws: wt[irr][c][k] = pw * w_irr[k][c] ----
__global__ void prep_w(const float* __restrict__ w0, const float* __restrict__ w1,
                       const float* __restrict__ w2, unsigned short* __restrict__ wt) {
  const int b = blockIdx.x;
  const int irr = b / 16;
  const int tile = b % 16;
  const int k0 = (tile >> 2) << 6;
  const int c0 = (tile & 3) << 6;
  const float* w = (irr == 0) ? w0 : ((irr == 1) ? w1 : w2);
  __shared__ float lt[64 * 65];
  const int t = threadIdx.x;
#pragma unroll
  for (int i = 0; i < 16; ++i) {
    int e = t + (i << 8);
    int kk = e >> 6, cc = e & 63;
    lt[cc * 65 + kk] = w[(k0 + kk) * 256 + (c0 + cc)];
  }
  __syncthreads();
#pragma unroll
  for (int i = 0; i < 16; ++i) {
    int e = t + (i << 8);
    int cc = e >> 6, kk = e & 63;
    wt[irr * 65536 + (c0 + cc) * 256 + (k0 + kk)] = f2bf(lt[cc * 65 + kk] * 0.0625f);
  }
}

// LDS->LDS convert: raw fp32 x[pos][k][m] -> bf16 planes [m][pos][k]
__device__ __forceinline__ void convert_raw(const float* __restrict__ raw_f,
                                            unsigned short* __restrict__ xs, int t) {
#pragma unroll
  for (int i = 0; i < 4; ++i) {
    const int u = t + (i << 9);        // 0..2047 = pos(3b) x k(8b)
    const int pos = u >> 8;
    const int k = u & 255;
    const float* s = raw_f + u * 9;
    float f0 = s[0], f1 = s[1], f2 = s[2], f3 = s[3], f4 = s[4];
    float f5 = s[5], f6 = s[6], f7 = s[7], f8 = s[8];
    unsigned short* base = xs + pos * XS_KS + k;
    unsigned p01 = cvt_pk_bf16(f0, f1);
    unsigned p23 = cvt_pk_bf16(f2, f3);
    unsigned p45 = cvt_pk_bf16(f4, f5);
    unsigned p67 = cvt_pk_bf16(f6, f7);
    base[0 * XS_MS] = (unsigned short)p01;
    base[1 * XS_MS] = (unsigned short)(p01 >> 16);
    base[2 * XS_MS] = (unsigned short)p23;
    base[3 * XS_MS] = (unsigned short)(p23 >> 16);
    base[4 * XS_MS] = (unsigned short)p45;
    base[5 * XS_MS] = (unsigned short)(p45 >> 16);
    base[6 * XS_MS] = (unsigned short)p67;
    base[7 * XS_MS] = (unsigned short)(p67 >> 16);
    base[8 * XS_MS] = f2bf(f8);
  }
}

// ---- main: 256 persistent blocks x 512 threads, 1 block/CU, NT=16 ----
__global__ __launch_bounds__(512, 2) void eqlin_main(
    const float* __restrict__ x, const unsigned short* __restrict__ wt,
    float* __restrict__ out) {
  extern __shared__ char smem[];
  char* raw = smem;                                            // 73728 B fp32
  const float* raw_f = reinterpret_cast<const float*>(raw);
  unsigned short* xs = reinterpret_cast<unsigned short*>(smem + RAW_BYTES);

  const int t = threadIdx.x;
  const long long blk = blockIdx.x;

  const int w = t >> 6;
  const int l = t & 63;
  const int cr = l & 15;          // A row sel / B col (=c in 16-wide group)
  const int kg = (l >> 4) << 3;   // k-chunk base 0/8/16/24
  const unsigned short* wtB = wt + ((w << 5) + cr) * 256 + kg;  // +ct*4096

  // A tile bases: rows 0-7 -> plane pA (pos=cr&7), rows 8-15 -> plane pB
  const bool hi = (cr >= 8);
  const unsigned short* xrow = xs + (cr & 7) * XS_KS + kg;
  const unsigned short* xa0 = xrow + 0 * XS_MS;              // T0 {0,0}
  const unsigned short* xa1 = xrow + (hi ? 2 : 1) * XS_MS;   // T1 {1,2}
  const unsigned short* xa2 = xrow + 3 * XS_MS;              // T2 {3,3}
  const unsigned short* xa3 = xrow + (hi ? 5 : 4) * XS_MS;   // T3 {4,5}
  const unsigned short* xa4 = xrow + (hi ? 7 : 6) * XS_MS;   // T4 {6,7}
  const unsigned short* xa5 = xrow + 8 * XS_MS;              // T5 {8,8}

  // DMA addressing: wave w copies pos row w (9216 B) of the tile
  const int dma_goff = w * 2304 + l * 4;   // floats
  char* dma_ldst = raw + w * 9216 + l * 16;

  float* stgw = reinterpret_cast<float*>(xs) + w * (POSB * STG_ROW);
  const int g = l >> 4;                 // 0..3; rows = g*4+j
  const int posb = (g & 1) << 2;        // pos = (g&1)*4 + j

  // ---- prologue: DMA tile 0, wait, convert ----
  {
    const float* x0 = x + blk * ((long long)NT * TILE_FLOATS) + dma_goff;
#pragma unroll
    for (int i = 0; i < 9; ++i) dma16(x0 + i * 256, dma_ldst + i * 1024);
    asm volatile("s_waitcnt vmcnt(0)" ::: "memory");
    bar_nodrain();
    convert_raw(raw_f, xs, t);
    bar_nodrain();
  }

  const int pAt[6] = {0, 1, 3, 4, 6, 8};
  const int pBt[6] = {0, 2, 3, 5, 7, 8};

#pragma unroll 1
  for (int it = 0; it < NT; ++it) {
    // ---- compute tile it from bf16 image ----
    f32x4 acc[2][6];  // [ct][tile]
#pragma unroll
    for (int ct = 0; ct < 2; ++ct)
#pragma unroll
      for (int T = 0; T < 6; ++T) acc[ct][T] = (f32x4){0.f, 0.f, 0.f, 0.f};

#pragma unroll 2
    for (int ks = 0; ks < 8; ++ks) {
      const int kk = ks << 5;
      s16x8 a0 = *reinterpret_cast<const s16x8*>(xa0 + kk);
      s16x8 a1 = *reinterpret_cast<const s16x8*>(xa1 + kk);
      s16x8 a2 = *reinterpret_cast<const s16x8*>(xa2 + kk);
      s16x8 a3 = *reinterpret_cast<const s16x8*>(xa3 + kk);
      s16x8 a4 = *reinterpret_cast<const s16x8*>(xa4 + kk);
      s16x8 a5 = *reinterpret_cast<const s16x8*>(xa5 + kk);
#pragma unroll
      for (int ct = 0; ct < 2; ++ct) {
        const unsigned short* wc = wtB + ct * 4096 + kk;
        s16x8 b0 = *reinterpret_cast<const s16x8*>(wc);            // irr0
        s16x8 b1 = *reinterpret_cast<const s16x8*>(wc + 65536);    // irr1
        s16x8 b2 = *reinterpret_cast<const s16x8*>(wc + 131072);   // irr2
        acc[ct][0] = __builtin_amdgcn_mfma_f32_16x16x32_bf16(a0, b0, acc[ct][0], 0, 0, 0);
        acc[ct][1] = __builtin_amdgcn_mfma_f32_16x16x32_bf16(a1, b1, acc[ct][1], 0, 0, 0);
        acc[ct][2] = __builtin_amdgcn_mfma_f32_16x16x32_bf16(a2, b1, acc[ct][2], 0, 0, 0);
        acc[ct][3] = __builtin_amdgcn_mfma_f32_16x16x32_bf16(a3, b2, acc[ct][3], 0, 0, 0);
        acc[ct][4] = __builtin_amdgcn_mfma_f32_16x16x32_bf16(a4, b2, acc[ct][4], 0, 0, 0);
        acc[ct][5] = __builtin_amdgcn_mfma_f32_16x16x32_bf16(a5, b2, acc[ct][5], 0, 0, 0);
      }
    }
    bar_nodrain();  // all waves done reading bf16 image; becomes stgw scratch

    // ---- issue DMA for tile it+1 (zero register cost; flies over outstage) ----
    if (it + 1 < NT) {
      const float* xn =
          x + blk * ((long long)NT * TILE_FLOATS) + (long long)(it + 1) * TILE_FLOATS + dma_goff;
#pragma unroll
      for (int i = 0; i < 9; ++i) dma16(xn + i * 256, dma_ldst + i * 1024);
      __builtin_amdgcn_sched_barrier(0);  // pin DMA before the stores below
    }

    // ---- out-stage: 2 chunks of 16 ch, per-wave slice, nt stores ----
    f32x4* o4 = reinterpret_cast<f32x4*>(out) + (blk * NT + it) * 4608 + w * 72;
#pragma unroll
    for (int ct = 0; ct < 2; ++ct) {
#pragma unroll
      for (int T = 0; T < 6; ++T) {
        const int m = (g < 2) ? pAt[T] : pBt[T];
        if (g < 2 || pAt[T] != pBt[T]) {  // rows 8-15 of single-plane tiles: dup
#pragma unroll
          for (int j = 0; j < 4; ++j)
            stgw[(posb + j) * STG_ROW + cr * 9 + m] = acc[ct][T][j];
        }
      }
      asm volatile("s_waitcnt lgkmcnt(0)" ::: "memory");
#pragma unroll
      for (int q = 0; q < 5; ++q) {
        const int e = l + (q << 6);                 // 0..287 float4s
        if (e < 288) {
          const int pos = (int)((unsigned)e / 36u);
          const int rem = e - pos * 36;
          f32x4 v = *reinterpret_cast<const f32x4*>(stgw + pos * STG_ROW + (rem << 2));
          __builtin_nontemporal_store(v, &o4[pos * 576 + ct * 36 + rem]);
        }
      }
      asm volatile("s_waitcnt lgkmcnt(0)" ::: "memory");  // reads done before next scatter
    }

    if (it + 1 < NT) {
      // own DMA done (oldest-first drain); own 10 newest (nt stores) keep flying
      asm volatile("s_waitcnt vmcnt(10)" ::: "memory");
      bar_nodrain();  // all waves' DMA landed + stgw reads done -> xs writable
      convert_raw(raw_f, xs, t);
      bar_nodrain();  // bf16 image ready for next compute
    }
  }
}

extern "C" void kernel_launch(void* const* d_in, const int* in_sizes, int n_in,
                              void* d_out, int out_size, void* d_ws, size_t ws_size,
                              hipStream_t stream) {
  const float* x = (const float*)d_in[0];
  const float* w0 = (const float*)d_in[1];
  const float* w1 = (const float*)d_in[2];
  const float* w2 = (const float*)d_in[3];
  unsigned short* wt = (unsigned short*)d_ws;  // 3*256*256 bf16 = 384 KB
  float* out = (float*)d_out;

  prep_w<<<48, 256, 0, stream>>>(w0, w1, w2, wt);

  (void)hipFuncSetAttribute(reinterpret_cast<const void*>(eqlin_main),
                            hipFuncAttributeMaxDynamicSharedMemorySize, SMEM_BYTES);
  eqlin_main<<<256, 512, SMEM_BYTES, stream>>>(x, wt, out);
}